// Round 1
// baseline (857.682 us; speedup 1.0000x reference)
//
#include <hip/hip_runtime.h>

#define TT 256
#define KK 64
#define BIGV 1e10f
#define BSTR 68   // padded LDS row stride (floats): quad index (row+k4)%8 -> conflict-free b128

__global__ __launch_bounds__(256, 2)
void sdtw_kernel(const float* __restrict__ X, const float* __restrict__ Y,
                 float* __restrict__ out) {
  const int b = blockIdx.x;
  const int type = blockIdx.y;  // 0: xy, 1: xx, 2: yy
  const float* Ap = (type == 2 ? Y : X) + (size_t)b * TT * KK;
  const float* Bp = (type == 1 ? X : Y) + (size_t)b * TT * KK;
  const float w = (type == 0) ? (1.0f / 512.0f) : (-0.5f / 512.0f);

  __shared__ float sB[TT * BSTR];   // 69632 B
  __shared__ float sbb[TT];         // 1 KB
  __shared__ float dbuf[3][TT];     // 3 KB rotating diagonal buffers

  const int t = threadIdx.x;

  // ---- stage B into LDS (coalesced global float4 reads) ----
  const float4* Bp4 = (const float4*)Bp;
  #pragma unroll
  for (int r = 0; r < 16; ++r) {
    int idx = (r << 8) + t;         // 4096 float4s total
    int row = idx >> 4;
    int k4  = idx & 15;
    float4 v = Bp4[idx];
    *(float4*)&sB[row * BSTR + (k4 << 2)] = v;
  }

  // ---- A row into registers ----
  float a[KK];
  {
    const float4* Ap4 = (const float4*)(Ap + t * KK);
    #pragma unroll
    for (int k4 = 0; k4 < 16; ++k4) {
      float4 v = Ap4[k4];
      a[4*k4+0] = v.x; a[4*k4+1] = v.y; a[4*k4+2] = v.z; a[4*k4+3] = v.w;
    }
  }
  float aa = 0.f;
  #pragma unroll
  for (int k = 0; k < KK; ++k) aa = fmaf(a[k], a[k], aa);
  aa *= 0.5f;

  __syncthreads();

  // ---- bb[t] = 0.5*||B_t||^2 from LDS; init diagonal buffers ----
  {
    float s0 = 0.f, s1 = 0.f, s2 = 0.f, s3 = 0.f;
    const float4* br4 = (const float4*)&sB[t * BSTR];
    #pragma unroll
    for (int k4 = 0; k4 < 16; ++k4) {
      float4 v = br4[k4];
      s0 = fmaf(v.x, v.x, s0); s1 = fmaf(v.y, v.y, s1);
      s2 = fmaf(v.z, v.z, s2); s3 = fmaf(v.w, v.w, s3);
    }
    sbb[t] = 0.5f * ((s0 + s1) + (s2 + s3));
    dbuf[0][t] = BIGV; dbuf[1][t] = BIGV; dbuf[2][t] = BIGV;
  }
  __syncthreads();

  // ---- wavefront DP: thread t computes row i=t+1; diagonal d = i + j ----
  float v_prev_own = BIGV;          // V[i][j-1] (my value from previous step)
  int cur = 2, p1 = 1, p2 = 0;      // d%3, (d-1)%3, (d-2)%3 at d=2
  for (int d = 2; d <= 2 * TT; ++d) {
    const int j = d - t - 1;
    float v_up, v_diag;             // V[i-1][j], V[i-1][j-1]
    if (t == 0) {
      v_up = BIGV;
      v_diag = (d == 2) ? 0.0f : BIGV;   // V[0][0]=0, V[0][j>=1]=BIG
    } else {
      v_up   = dbuf[p1][t - 1];
      v_diag = dbuf[p2][t - 1];
    }
    float vnew = BIGV;
    if (j >= 1 && j <= TT) {
      const float4* br4 = (const float4*)&sB[(j - 1) * BSTR];
      float d0 = 0.f, d1 = 0.f, d2 = 0.f, d3 = 0.f;
      #pragma unroll
      for (int k4 = 0; k4 < 16; ++k4) {
        float4 bv = br4[k4];
        d0 = fmaf(a[4*k4+0], bv.x, d0);
        d1 = fmaf(a[4*k4+1], bv.y, d1);
        d2 = fmaf(a[4*k4+2], bv.z, d2);
        d3 = fmaf(a[4*k4+3], bv.w, d3);
      }
      float c = aa + sbb[j - 1] - ((d0 + d1) + (d2 + d3));
      float v_left = (j == 1) ? BIGV : v_prev_own;
      float m = fminf(fminf(v_left, v_diag), v_up);
      float s = m - __logf(__expf(m - v_left) + __expf(m - v_diag) + __expf(m - v_up));
      vnew = c + s;
      v_prev_own = vnew;
    }
    dbuf[cur][t] = vnew;
    int tmp = p2; p2 = p1; p1 = cur; cur = tmp;
    __syncthreads();
  }

  // thread 255 holds V[256][256]
  if (t == TT - 1) atomicAdd(out, w * v_prev_own);
}

extern "C" void kernel_launch(void* const* d_in, const int* in_sizes, int n_in,
                              void* d_out, int out_size, void* d_ws, size_t ws_size,
                              hipStream_t stream) {
  const float* X = (const float*)d_in[0];
  const float* Y = (const float*)d_in[1];
  float* out = (float*)d_out;
  hipMemsetAsync(out, 0, sizeof(float) * out_size, stream);
  dim3 grid(512, 3);
  dim3 block(256);
  sdtw_kernel<<<grid, block, 0, stream>>>(X, Y, out);
}

// Round 2
// 393.289 us; speedup vs baseline: 2.1808x; 2.1808x over previous
//
#include <hip/hip_runtime.h>

typedef _Float16 h2 __attribute__((ext_vector_type(2)));
typedef _Float16 h4 __attribute__((ext_vector_type(4)));

#define TT 256
#define KK 64
#define BIGV 1e10f
#define SROW 72   // halves per B-row in LDS: 144 B = 9*16 -> b128 quad index cycles all 8 -> conflict-free

__device__ __forceinline__ float softmin3(float a, float b, float c) {
  float m = fminf(fminf(a, b), c);
  return m - __logf(__expf(m - a) + __expf(m - b) + __expf(m - c));
}

__global__ __launch_bounds__(128, 2)
void sdtw_kernel(const float* __restrict__ X, const float* __restrict__ Y,
                 float* __restrict__ out) {
  const int b = blockIdx.x;
  const int type = blockIdx.y;  // 0: xy, 1: xx, 2: yy
  const float* Ap = (type == 2 ? Y : X) + (size_t)b * TT * KK;
  const float* Bp = (type == 1 ? X : Y) + (size_t)b * TT * KK;
  const float w = (type == 0) ? (1.0f / 512.0f) : (-0.5f / 512.0f);

  __shared__ _Float16 sB[TT * SROW];   // 36864 B
  __shared__ float sbb[TT];            // 1 KB
  __shared__ float vbuf[3][128];       // 1.5 KB

  const int t = threadIdx.x;

  // ---- coalesced stage of a (256x64 f32) matrix into sB as f16 ----
  auto stage = [&](const float* src) {
    const float4* s4 = (const float4*)src;
    #pragma unroll
    for (int it = 0; it < 32; ++it) {
      int p = it * 128 + t;            // float4 index 0..4095, lane-consecutive
      int row = p >> 4, ch = p & 15;
      float4 v = s4[p];
      h4 pk = { (_Float16)v.x, (_Float16)v.y, (_Float16)v.z, (_Float16)v.w };
      *(h4*)&sB[row * SROW + (ch << 2)] = pk;   // 8B aligned ds_write_b64
    }
  };

  // Phase 1: A -> LDS f16 -> own 2 rows to registers (+aa)
  stage(Ap);
  __syncthreads();
  h2 a1[32], a2[32];
  float aa1 = 0.f, aa2 = 0.f;
  {
    const float4* r1 = (const float4*)&sB[(2 * t) * SROW];
    const float4* r2 = (const float4*)&sB[(2 * t + 1) * SROW];
    #pragma unroll
    for (int c = 0; c < 8; ++c) {
      float4 u = r1[c];
      a1[4*c+0] = __builtin_bit_cast(h2, u.x);
      a1[4*c+1] = __builtin_bit_cast(h2, u.y);
      a1[4*c+2] = __builtin_bit_cast(h2, u.z);
      a1[4*c+3] = __builtin_bit_cast(h2, u.w);
      float4 v = r2[c];
      a2[4*c+0] = __builtin_bit_cast(h2, v.x);
      a2[4*c+1] = __builtin_bit_cast(h2, v.y);
      a2[4*c+2] = __builtin_bit_cast(h2, v.z);
      a2[4*c+3] = __builtin_bit_cast(h2, v.w);
    }
    #pragma unroll
    for (int c = 0; c < 32; ++c) {
      aa1 = __builtin_amdgcn_fdot2(a1[c], a1[c], aa1, false);
      aa2 = __builtin_amdgcn_fdot2(a2[c], a2[c], aa2, false);
    }
    aa1 *= 0.5f; aa2 *= 0.5f;
  }
  __syncthreads();

  // Phase 2: B -> LDS f16; bb from LDS; init diagonal buffers
  stage(Bp);
  __syncthreads();
  {
    #pragma unroll
    for (int rr = 0; rr < 2; ++rr) {
      int r = 2 * t + rr;
      const float4* br = (const float4*)&sB[r * SROW];
      float s = 0.f;
      #pragma unroll
      for (int c = 0; c < 8; ++c) {
        float4 u = br[c];
        h2 b0 = __builtin_bit_cast(h2, u.x), b1 = __builtin_bit_cast(h2, u.y);
        h2 b2 = __builtin_bit_cast(h2, u.z), b3 = __builtin_bit_cast(h2, u.w);
        s = __builtin_amdgcn_fdot2(b0, b0, s, false);
        s = __builtin_amdgcn_fdot2(b1, b1, s, false);
        s = __builtin_amdgcn_fdot2(b2, b2, s, false);
        s = __builtin_amdgcn_fdot2(b3, b3, s, false);
      }
      sbb[r] = 0.5f * s;
    }
    vbuf[0][t] = BIGV; vbuf[1][t] = BIGV; vbuf[2][t] = BIGV;
  }
  __syncthreads();

  // ---- wavefront DP: thread t owns rows i1=2t+1, i2=2t+2; at step s computes column j=s-t ----
  float vL1 = BIGV, vL2 = BIGV;   // V[i1][j-1], V[i2][j-1]
  int cur = 2, p1 = 1, p2 = 0;
  for (int s = 1; s <= TT + 127; ++s) {
    const int j = s - t;
    float up1, dg1;                 // V[i1-1][j], V[i1-1][j-1]  (thread t-1's i2 values)
    if (t == 0) {
      up1 = BIGV;
      dg1 = (s == 1) ? 0.0f : BIGV;   // V[0][0]=0, else BIG
    } else {
      up1 = vbuf[p1][t - 1];
      dg1 = vbuf[p2][t - 1];
    }
    float wv = BIGV;
    if (j >= 1 && j <= TT) {
      const float4* br = (const float4*)&sB[(j - 1) * SROW];
      float d1 = 0.f, d2 = 0.f;
      #pragma unroll
      for (int c = 0; c < 8; ++c) {
        float4 u = br[c];
        h2 b0 = __builtin_bit_cast(h2, u.x), b1 = __builtin_bit_cast(h2, u.y);
        h2 b2 = __builtin_bit_cast(h2, u.z), b3 = __builtin_bit_cast(h2, u.w);
        d1 = __builtin_amdgcn_fdot2(a1[4*c+0], b0, d1, false);
        d2 = __builtin_amdgcn_fdot2(a2[4*c+0], b0, d2, false);
        d1 = __builtin_amdgcn_fdot2(a1[4*c+1], b1, d1, false);
        d2 = __builtin_amdgcn_fdot2(a2[4*c+1], b1, d2, false);
        d1 = __builtin_amdgcn_fdot2(a1[4*c+2], b2, d1, false);
        d2 = __builtin_amdgcn_fdot2(a2[4*c+2], b2, d2, false);
        d1 = __builtin_amdgcn_fdot2(a1[4*c+3], b3, d1, false);
        d2 = __builtin_amdgcn_fdot2(a2[4*c+3], b3, d2, false);
      }
      float bbj = sbb[j - 1];
      float c1 = aa1 + bbj - d1;
      float c2 = aa2 + bbj - d2;
      float edge = (j == 1) ? BIGV : vL1;
      float l1 = (j == 1) ? BIGV : vL1;
      float v1 = c1 + softmin3(l1, dg1, up1);
      float dg2 = edge;                         // V[i1][j-1] (pre-update)
      float l2 = (j == 1) ? BIGV : vL2;
      float v2 = c2 + softmin3(l2, dg2, v1);    // up2 = v1
      vL1 = v1; vL2 = v2; wv = v2;
    }
    vbuf[cur][t] = wv;
    int tmp = p2; p2 = p1; p1 = cur; cur = tmp;
    __syncthreads();
  }

  // thread 127 finishes cell (256,256) at the last step
  if (t == 127) atomicAdd(out, w * vL2);
}

extern "C" void kernel_launch(void* const* d_in, const int* in_sizes, int n_in,
                              void* d_out, int out_size, void* d_ws, size_t ws_size,
                              hipStream_t stream) {
  const float* X = (const float*)d_in[0];
  const float* Y = (const float*)d_in[1];
  float* out = (float*)d_out;
  hipMemsetAsync(out, 0, sizeof(float) * out_size, stream);
  dim3 grid(512, 3);
  dim3 block(128);
  sdtw_kernel<<<grid, block, 0, stream>>>(X, Y, out);
}

// Round 3
// 245.328 us; speedup vs baseline: 3.4961x; 1.6031x over previous
//
#include <hip/hip_runtime.h>

typedef _Float16 h2 __attribute__((ext_vector_type(2)));
typedef _Float16 h4 __attribute__((ext_vector_type(4)));
typedef _Float16 h8 __attribute__((ext_vector_type(8)));
typedef float f4 __attribute__((ext_vector_type(4)));

#define TT 256
#define KK 64
#define BIGV 1e10f
#define SROW 72           // halves per staged row (144 B = 9*16: b128-aligned, 2-way-free banks)
#define SLAB 81664        // bytes per problem slab: 319 steps * 256 rows * 1B fp8
#define NPROB 1536

__device__ __forceinline__ float softmin3(float a, float b, float c) {
  float m = fminf(fminf(a, b), c);
  return m - __logf(__expf(m - a) + __expf(m - b) + __expf(m - c));
}

// ---------------- Kernel 1: C = aa + bb - A.B^T via MFMA, fp8 diag-major out ----------------
__global__ __launch_bounds__(256, 1)
void cost_kernel(const float* __restrict__ X, const float* __restrict__ Y,
                 unsigned char* __restrict__ ws, int p0) {
  const int p = p0 + blockIdx.x;
  const int type = p >> 9;
  const int b = p & 511;
  const float* Ap = (type == 2 ? Y : X) + (size_t)b * TT * KK;
  const float* Bp = (type == 1 ? X : Y) + (size_t)b * TT * KK;

  __shared__ _Float16 sA[TT * SROW];          // 36864 B
  __shared__ _Float16 sB[TT * SROW];          // 36864 B
  __shared__ float saa[TT];                   // 1 KB
  __shared__ float sbb[TT];                   // 1 KB
  __shared__ unsigned int stg[4][64 * 18];    // per-wave 64 cols x 72 B (18 u32) = 18432 B

  const int tid = threadIdx.x;
  const int w = tid >> 6, l = tid & 63;

  // ---- stage A,B -> LDS f16 (coalesced) ----
  {
    const float4* a4 = (const float4*)Ap;
    const float4* b4 = (const float4*)Bp;
    #pragma unroll
    for (int it = 0; it < 16; ++it) {
      int pp = it * 256 + tid;
      int row = pp >> 4, ch = pp & 15;
      float4 v = a4[pp];
      h4 pa = {(_Float16)v.x, (_Float16)v.y, (_Float16)v.z, (_Float16)v.w};
      *(h4*)&sA[row * SROW + (ch << 2)] = pa;
      float4 u = b4[pp];
      h4 pb = {(_Float16)u.x, (_Float16)u.y, (_Float16)u.z, (_Float16)u.w};
      *(h4*)&sB[row * SROW + (ch << 2)] = pb;
    }
  }
  __syncthreads();
  // ---- row norms ----
  {
    float sa = 0.f, sb2 = 0.f;
    #pragma unroll
    for (int c = 0; c < 32; ++c) {
      h2 va = *(const h2*)&sA[tid * SROW + 2 * c];
      sa = __builtin_amdgcn_fdot2(va, va, sa, false);
      h2 vb = *(const h2*)&sB[tid * SROW + 2 * c];
      sb2 = __builtin_amdgcn_fdot2(vb, vb, sb2, false);
    }
    saa[tid] = 0.5f * sa;
    sbb[tid] = 0.5f * sb2;
  }
  __syncthreads();

  // ---- MFMA: wave w computes 64-row band ----
  const int band = w * 64;
  const int hk = l >> 4;    // k-group 0..3 (8 halves each within K=32)
  const int lr = l & 15;    // row/col within 16-tile
  h8 af[4][2];
  #pragma unroll
  for (int rt = 0; rt < 4; ++rt)
    #pragma unroll
    for (int kk = 0; kk < 2; ++kk)
      af[rt][kk] = *(const h8*)&sA[(band + rt * 16 + lr) * SROW + kk * 32 + hk * 8];

  unsigned int* slab32 = (unsigned int*)(ws + (size_t)blockIdx.x * SLAB);
  const int b4q = band >> 2;   // 16*w

  for (int g = 0; g < 4; ++g) {
    #pragma unroll
    for (int cjl = 0; cjl < 4; ++cjl) {
      int cj = g * 4 + cjl;
      h8 bf0 = *(const h8*)&sB[(cj * 16 + lr) * SROW + hk * 8];
      h8 bf1 = *(const h8*)&sB[(cj * 16 + lr) * SROW + 32 + hk * 8];
      float bbv = sbb[cj * 16 + lr];
      #pragma unroll
      for (int rt = 0; rt < 4; ++rt) {
        f4 acc = {0.f, 0.f, 0.f, 0.f};
        acc = __builtin_amdgcn_mfma_f32_16x16x32_f16(af[rt][0], bf0, acc, 0, 0, 0);
        acc = __builtin_amdgcn_mfma_f32_16x16x32_f16(af[rt][1], bf1, acc, 0, 0, 0);
        int r0 = band + rt * 16 + hk * 4;
        f4 aav = *(const f4*)&saa[r0];
        float c0 = aav.x + bbv - acc.x;
        float c1 = aav.y + bbv - acc.y;
        float c2 = aav.z + bbv - acc.z;
        float c3 = aav.w + bbv - acc.w;
        int pk = __builtin_amdgcn_cvt_pk_fp8_f32(c0, c1, 0, false);
        pk = __builtin_amdgcn_cvt_pk_fp8_f32(c2, c3, pk, true);
        stg[w][(cjl * 16 + lr) * 18 + rt * 4 + hk] = (unsigned int)pk;
      }
    }
    // ---- flush group g: coalesced diag-major stores ----
    int gc0 = g * 64;
    int s_lo = gc0 + b4q;
    int q = l & 15;
    int su = l >> 4;
    #pragma unroll
    for (int ss = 0; ss < 20; ++ss) {
      int s1 = s_lo + ss * 4 + su;
      int j1 = s1 - (b4q + q);
      if (j1 >= gc0 && j1 < gc0 + 64) {
        unsigned int val = stg[w][(j1 - gc0) * 18 + q];
        slab32[s1 * 64 + w * 16 + q] = val;
      }
    }
  }
}

// ---------------- Kernel 2: wave-synchronous DP, 4 rows/thread, no barriers ----------------
__global__ __launch_bounds__(64, 2)
void dp_kernel(const unsigned char* __restrict__ ws, float* __restrict__ out, int p0) {
  const int p = p0 + blockIdx.x;
  const int type = p >> 9;
  const float wgt = (type == 0) ? (1.0f / 512.0f) : (-0.5f / 512.0f);
  const int t = threadIdx.x;
  const unsigned int* slab32 = (const unsigned int*)(ws + (size_t)blockIdx.x * SLAB);

  unsigned int cp[8];
  #pragma unroll
  for (int u = 0; u < 8; ++u) cp[u] = slab32[u * 64 + t];   // steps 1..8 (s1 = 0..7)

  float vL1 = BIGV, vL2 = BIGV, vL3 = BIGV, vL4 = BIGV;
  float v4s1 = BIGV, v4s2 = BIGV;   // my row-4 value at step s-1, s-2

  for (int sb = 1; sb <= 313; sb += 8) {
    #pragma unroll
    for (int u = 0; u < 8; ++u) {
      int s = sb + u;
      float up1 = __shfl_up(v4s1, 1);   // V[4t][j]   (neighbor, step s-1)
      float dg1 = __shfl_up(v4s2, 1);   // V[4t][j-1] (neighbor, step s-2)
      if (t == 0) { up1 = BIGV; dg1 = (s == 1) ? 0.0f : BIGV; }
      unsigned int cw = cp[u];
      int s1n = (s + 7 <= 318) ? s + 7 : 318;      // prefetch step s+8
      cp[u] = slab32[s1n * 64 + t];
      int j = s - t;
      bool act = (j >= 1 && j <= TT);
      float c0 = __builtin_amdgcn_cvt_f32_fp8((int)cw, 0);
      float c1 = __builtin_amdgcn_cvt_f32_fp8((int)cw, 1);
      float c2 = __builtin_amdgcn_cvt_f32_fp8((int)cw, 2);
      float c3 = __builtin_amdgcn_cvt_f32_fp8((int)cw, 3);
      float v1 = c0 + softmin3(vL1, dg1, up1);
      float v2 = c1 + softmin3(vL2, vL1, v1);
      float v3 = c2 + softmin3(vL3, vL2, v2);
      float v4 = c3 + softmin3(vL4, vL3, v3);
      if (act) {
        vL1 = v1; vL2 = v2; vL3 = v3; vL4 = v4;
        v4s2 = v4s1; v4s1 = v4;
      }
    }
  }
  if (t == 63) atomicAdd(out, wgt * vL4);
}

// ---------------- Fallback: round-2 fused kernel (if ws too small) ----------------
__global__ __launch_bounds__(128, 2)
void sdtw_fused(const float* __restrict__ X, const float* __restrict__ Y,
                float* __restrict__ out) {
  const int b = blockIdx.x;
  const int type = blockIdx.y;
  const float* Ap = (type == 2 ? Y : X) + (size_t)b * TT * KK;
  const float* Bp = (type == 1 ? X : Y) + (size_t)b * TT * KK;
  const float w = (type == 0) ? (1.0f / 512.0f) : (-0.5f / 512.0f);

  __shared__ _Float16 sFB[TT * 72];
  __shared__ float sbb[TT];
  __shared__ float vbuf[3][128];
  const int t = threadIdx.x;

  auto stage = [&](const float* src) {
    const float4* s4 = (const float4*)src;
    #pragma unroll
    for (int it = 0; it < 32; ++it) {
      int pq = it * 128 + t;
      int row = pq >> 4, ch = pq & 15;
      float4 v = s4[pq];
      h4 pk = {(_Float16)v.x, (_Float16)v.y, (_Float16)v.z, (_Float16)v.w};
      *(h4*)&sFB[row * 72 + (ch << 2)] = pk;
    }
  };
  stage(Ap);
  __syncthreads();
  h2 a1[32], a2[32];
  float aa1 = 0.f, aa2 = 0.f;
  {
    #pragma unroll
    for (int c = 0; c < 32; ++c) {
      a1[c] = *(const h2*)&sFB[(2 * t) * 72 + 2 * c];
      a2[c] = *(const h2*)&sFB[(2 * t + 1) * 72 + 2 * c];
    }
    #pragma unroll
    for (int c = 0; c < 32; ++c) {
      aa1 = __builtin_amdgcn_fdot2(a1[c], a1[c], aa1, false);
      aa2 = __builtin_amdgcn_fdot2(a2[c], a2[c], aa2, false);
    }
    aa1 *= 0.5f; aa2 *= 0.5f;
  }
  __syncthreads();
  stage(Bp);
  __syncthreads();
  {
    #pragma unroll
    for (int rr = 0; rr < 2; ++rr) {
      int r = 2 * t + rr;
      float s = 0.f;
      #pragma unroll
      for (int c = 0; c < 32; ++c) {
        h2 bv = *(const h2*)&sFB[r * 72 + 2 * c];
        s = __builtin_amdgcn_fdot2(bv, bv, s, false);
      }
      sbb[r] = 0.5f * s;
    }
    vbuf[0][t] = BIGV; vbuf[1][t] = BIGV; vbuf[2][t] = BIGV;
  }
  __syncthreads();
  float vL1 = BIGV, vL2 = BIGV;
  int cur = 2, p1 = 1, p2 = 0;
  for (int s = 1; s <= TT + 127; ++s) {
    const int j = s - t;
    float up1, dg1;
    if (t == 0) { up1 = BIGV; dg1 = (s == 1) ? 0.0f : BIGV; }
    else { up1 = vbuf[p1][t - 1]; dg1 = vbuf[p2][t - 1]; }
    float wv = BIGV;
    if (j >= 1 && j <= TT) {
      float d1 = 0.f, d2 = 0.f;
      #pragma unroll
      for (int c = 0; c < 32; ++c) {
        h2 bv = *(const h2*)&sFB[(j - 1) * 72 + 2 * c];
        d1 = __builtin_amdgcn_fdot2(a1[c], bv, d1, false);
        d2 = __builtin_amdgcn_fdot2(a2[c], bv, d2, false);
      }
      float bbj = sbb[j - 1];
      float c1 = aa1 + bbj - d1;
      float c2 = aa2 + bbj - d2;
      float l1 = (j == 1) ? BIGV : vL1;
      float v1 = c1 + softmin3(l1, dg1, up1);
      float dg2 = l1;
      float l2 = (j == 1) ? BIGV : vL2;
      float v2 = c2 + softmin3(l2, dg2, v1);
      vL1 = v1; vL2 = v2; wv = v2;
    }
    vbuf[cur][t] = wv;
    int tmp = p2; p2 = p1; p1 = cur; cur = tmp;
    __syncthreads();
  }
  if (t == 127) atomicAdd(out, w * vL2);
}

extern "C" void kernel_launch(void* const* d_in, const int* in_sizes, int n_in,
                              void* d_out, int out_size, void* d_ws, size_t ws_size,
                              hipStream_t stream) {
  const float* X = (const float*)d_in[0];
  const float* Y = (const float*)d_in[1];
  float* out = (float*)d_out;
  hipMemsetAsync(out, 0, sizeof(float) * out_size, stream);

  size_t chunk = ws_size / SLAB;
  if (chunk >= 1) {
    if (chunk > NPROB) chunk = NPROB;
    unsigned char* ws = (unsigned char*)d_ws;
    for (int q0 = 0; q0 < NPROB; q0 += (int)chunk) {
      int n = (NPROB - q0 < (int)chunk) ? NPROB - q0 : (int)chunk;
      cost_kernel<<<n, 256, 0, stream>>>(X, Y, ws, q0);
      dp_kernel<<<n, 64, 0, stream>>>(ws, out, q0);
    }
  } else {
    dim3 grid(512, 3);
    sdtw_fused<<<grid, 128, 0, stream>>>(X, Y, out);
  }
}

// Round 4
// 182.839 us; speedup vs baseline: 4.6909x; 1.3418x over previous
//
#include <hip/hip_runtime.h>

typedef _Float16 h2 __attribute__((ext_vector_type(2)));
typedef _Float16 h4 __attribute__((ext_vector_type(4)));
typedef _Float16 h8 __attribute__((ext_vector_type(8)));
typedef float f4 __attribute__((ext_vector_type(4)));

#define TT 256
#define KK 64
#define BIGV 1e10f
#define SROW 72           // halves per staged row (144 B = 9*16: b128-aligned, conflict-friendly)
#define SLAB 81664        // bytes per problem slab: 319 steps * 64 lanes * 4B (fp8x4)
#define NPROB 1536
#define LOG2E 1.44269504f
#define LN2 0.69314718f

// softmin in log2-scaled domain: values are V*log2(e); exact softmin correspondence.
__device__ __forceinline__ float softmin3b(float a, float b, float c) {
  float m, d, M;
  asm("v_min3_f32 %0, %1, %2, %3" : "=v"(m) : "v"(a), "v"(b), "v"(c));
  asm("v_max3_f32 %0, %1, %2, %3" : "=v"(M) : "v"(a), "v"(b), "v"(c));
  asm("v_med3_f32 %0, %1, %2, %3" : "=v"(d) : "v"(a), "v"(b), "v"(c));
  float s = 1.0f + __builtin_amdgcn_exp2f(m - d) + __builtin_amdgcn_exp2f(m - M);
  return m - __log2f(s);
}

// ---------------- Kernel 1: C' = log2e*(aa + bb - A.B^T) via MFMA, fp8 diag-major out --------
__global__ __launch_bounds__(256, 2)
void cost_kernel(const float* __restrict__ X, const float* __restrict__ Y,
                 unsigned char* __restrict__ ws, int p0) {
  const int p = p0 + blockIdx.x;
  const int type = p >> 9;
  const int b = p & 511;
  const float* Ap = (type == 2 ? Y : X) + (size_t)b * TT * KK;
  const float* Bp = (type == 1 ? X : Y) + (size_t)b * TT * KK;

  __shared__ _Float16 sB[TT * SROW];          // 36864 B
  __shared__ float saa[TT];                   // 1 KB  (pre-scaled by 0.5*log2e)
  __shared__ float sbb[TT];                   // 1 KB
  __shared__ unsigned int stg[4][64 * 18];    // 18432 B   total LDS = 57344 B -> 2 blocks/CU

  const int tid = threadIdx.x;
  const int w = tid >> 6, l = tid & 63;
  unsigned int* slab32 = (unsigned int*)(ws + (size_t)blockIdx.x * SLAB);

  // ---- zero the invalid (never-written) slab entries so dp can run unguarded ----
  for (int e = tid; e < 319 * 64; e += 256) {
    int s1 = e >> 6, tt = e & 63;
    if (s1 < tt || s1 > tt + 255) slab32[e] = 0u;
  }

  // ---- stage B -> LDS f16 (coalesced) ----
  {
    const float4* b4 = (const float4*)Bp;
    #pragma unroll
    for (int it = 0; it < 16; ++it) {
      int pp = it * 256 + tid;
      int row = pp >> 4, ch = pp & 15;
      float4 u = b4[pp];
      h4 pb = {(_Float16)u.x, (_Float16)u.y, (_Float16)u.z, (_Float16)u.w};
      *(h4*)&sB[row * SROW + (ch << 2)] = pb;
    }
  }

  // ---- row norms from global (f32), pre-scaled by 0.5*log2e ----
  {
    const float4* ar = (const float4*)(Ap + tid * KK);
    const float4* br = (const float4*)(Bp + tid * KK);
    float sa = 0.f, sb2 = 0.f;
    #pragma unroll
    for (int c = 0; c < 16; ++c) {
      float4 u = ar[c];
      sa = fmaf(u.x, u.x, fmaf(u.y, u.y, fmaf(u.z, u.z, fmaf(u.w, u.w, sa))));
      float4 v = br[c];
      sb2 = fmaf(v.x, v.x, fmaf(v.y, v.y, fmaf(v.z, v.z, fmaf(v.w, v.w, sb2))));
    }
    saa[tid] = 0.5f * LOG2E * sa;
    sbb[tid] = 0.5f * LOG2E * sb2;
  }

  // ---- A fragments: direct global -> reg (f32 -> f16) ----
  const int band = w * 64;
  const int hk = l >> 4;    // k-group 0..3
  const int lr = l & 15;    // row within 16-tile
  h8 af[4][2];
  #pragma unroll
  for (int rt = 0; rt < 4; ++rt)
    #pragma unroll
    for (int kk = 0; kk < 2; ++kk) {
      const float4* src = (const float4*)(Ap + (band + rt * 16 + lr) * KK + kk * 32 + hk * 8);
      float4 x = src[0], y = src[1];
      af[rt][kk] = (h8){(_Float16)x.x, (_Float16)x.y, (_Float16)x.z, (_Float16)x.w,
                        (_Float16)y.x, (_Float16)y.y, (_Float16)y.z, (_Float16)y.w};
    }
  __syncthreads();

  const int b4q = band >> 2;   // 16*w

  for (int g = 0; g < 4; ++g) {
    #pragma unroll
    for (int cjl = 0; cjl < 4; ++cjl) {
      int cj = g * 4 + cjl;
      h8 bf0 = *(const h8*)&sB[(cj * 16 + lr) * SROW + hk * 8];
      h8 bf1 = *(const h8*)&sB[(cj * 16 + lr) * SROW + 32 + hk * 8];
      float bbv = sbb[cj * 16 + lr];
      #pragma unroll
      for (int rt = 0; rt < 4; ++rt) {
        f4 acc = {0.f, 0.f, 0.f, 0.f};
        acc = __builtin_amdgcn_mfma_f32_16x16x32_f16(af[rt][0], bf0, acc, 0, 0, 0);
        acc = __builtin_amdgcn_mfma_f32_16x16x32_f16(af[rt][1], bf1, acc, 0, 0, 0);
        int r0 = band + rt * 16 + hk * 4;
        f4 aav = *(const f4*)&saa[r0];
        float c0 = fmaf(-LOG2E, acc.x, aav.x + bbv);
        float c1 = fmaf(-LOG2E, acc.y, aav.y + bbv);
        float c2 = fmaf(-LOG2E, acc.z, aav.z + bbv);
        float c3 = fmaf(-LOG2E, acc.w, aav.w + bbv);
        int pk = __builtin_amdgcn_cvt_pk_fp8_f32(c0, c1, 0, false);
        pk = __builtin_amdgcn_cvt_pk_fp8_f32(c2, c3, pk, true);
        stg[w][(cjl * 16 + lr) * 18 + rt * 4 + hk] = (unsigned int)pk;
      }
    }
    // ---- flush group g: coalesced diag-major stores ----
    int gc0 = g * 64;
    int s_lo = gc0 + b4q;
    int q = l & 15;
    int su = l >> 4;
    #pragma unroll
    for (int ss = 0; ss < 20; ++ss) {
      int s1 = s_lo + ss * 4 + su;
      int j1 = s1 - (b4q + q);
      if (j1 >= gc0 && j1 < gc0 + 64) {
        unsigned int val = stg[w][(j1 - gc0) * 18 + q];
        slab32[s1 * 64 + w * 16 + q] = val;
      }
    }
  }
}

// ---------------- Kernel 2: wave-synchronous DP, 4 rows/thread, exp2 domain ----------------
__global__ __launch_bounds__(64, 2)
void dp_kernel(const unsigned char* __restrict__ ws, float* __restrict__ out, int p0) {
  const int p = p0 + blockIdx.x;
  const int type = p >> 9;
  const float wgt = (type == 0) ? (LN2 / 512.0f) : (-LN2 / 1024.0f);  // x ln2: back to e-domain
  const int t = threadIdx.x;
  const unsigned int* slab32 = (const unsigned int*)(ws + (size_t)blockIdx.x * SLAB);

  unsigned int cp[8];
  #pragma unroll
  for (int u = 0; u < 8; ++u) cp[u] = slab32[u * 64 + t];   // steps 1..8

  float vL1 = BIGV, vL2 = BIGV, vL3 = BIGV, vL4 = BIGV;     // V[i_r][j-1]
  float dg = (t == 0) ? 0.0f : BIGV;                        // V[i1-1][j-1]; s=1: V[0][0]=0

  // main: s = 1..312 (39 blocks of 8), tail: s = 313..319
  for (int sb = 1; sb <= 305; sb += 8) {
    #pragma unroll
    for (int u = 0; u < 8; ++u) {
      const int s = sb + u;
      float up1 = __shfl_up(vL4, 1);          // neighbor v4 from step s-1
      if (t == 0) up1 = BIGV;
      unsigned int cw = cp[u];
      int s1n = s + 7; if (s1n > 318) s1n = 318;
      cp[u] = slab32[s1n * 64 + t];           // prefetch step s+8
      float c0 = __builtin_amdgcn_cvt_f32_fp8((int)cw, 0);
      float c1 = __builtin_amdgcn_cvt_f32_fp8((int)cw, 1);
      float c2 = __builtin_amdgcn_cvt_f32_fp8((int)cw, 2);
      float c3 = __builtin_amdgcn_cvt_f32_fp8((int)cw, 3);
      float v1 = c0 + softmin3b(vL1, dg, up1);
      float v2 = c1 + softmin3b(vL2, vL1, v1);
      float v3 = c2 + softmin3b(vL3, vL2, v2);
      float v4 = c3 + softmin3b(vL4, vL3, v3);
      vL1 = v1; vL2 = v2; vL3 = v3; vL4 = v4; dg = up1;
    }
  }
  #pragma unroll
  for (int u = 0; u < 7; ++u) {               // s = 313..319, no prefetch
    float up1 = __shfl_up(vL4, 1);
    if (t == 0) up1 = BIGV;
    unsigned int cw = cp[u];
    float c0 = __builtin_amdgcn_cvt_f32_fp8((int)cw, 0);
    float c1 = __builtin_amdgcn_cvt_f32_fp8((int)cw, 1);
    float c2 = __builtin_amdgcn_cvt_f32_fp8((int)cw, 2);
    float c3 = __builtin_amdgcn_cvt_f32_fp8((int)cw, 3);
    float v1 = c0 + softmin3b(vL1, dg, up1);
    float v2 = c1 + softmin3b(vL2, vL1, v1);
    float v3 = c2 + softmin3b(vL3, vL2, v2);
    float v4 = c3 + softmin3b(vL4, vL3, v3);
    vL1 = v1; vL2 = v2; vL3 = v3; vL4 = v4; dg = up1;
  }
  if (t == 63) atomicAdd(out, wgt * vL4);     // V'[256][256] in log2 domain
}

// ---------------- Fallback: fused kernel (if ws too small), raw e-domain ----------------
__global__ __launch_bounds__(128, 2)
void sdtw_fused(const float* __restrict__ X, const float* __restrict__ Y,
                float* __restrict__ out) {
  const int b = blockIdx.x;
  const int type = blockIdx.y;
  const float* Ap = (type == 2 ? Y : X) + (size_t)b * TT * KK;
  const float* Bp = (type == 1 ? X : Y) + (size_t)b * TT * KK;
  const float w = (type == 0) ? (1.0f / 512.0f) : (-0.5f / 512.0f);

  __shared__ _Float16 sFB[TT * 72];
  __shared__ float sbb[TT];
  __shared__ float vbuf[3][128];
  const int t = threadIdx.x;

  auto stage = [&](const float* src) {
    const float4* s4 = (const float4*)src;
    #pragma unroll
    for (int it = 0; it < 32; ++it) {
      int pq = it * 128 + t;
      int row = pq >> 4, ch = pq & 15;
      float4 v = s4[pq];
      h4 pk = {(_Float16)v.x, (_Float16)v.y, (_Float16)v.z, (_Float16)v.w};
      *(h4*)&sFB[row * 72 + (ch << 2)] = pk;
    }
  };
  auto softmin3 = [](float a, float b2, float c) {
    float m = fminf(fminf(a, b2), c);
    return m - __logf(__expf(m - a) + __expf(m - b2) + __expf(m - c));
  };
  stage(Ap);
  __syncthreads();
  h2 a1[32], a2[32];
  float aa1 = 0.f, aa2 = 0.f;
  {
    #pragma unroll
    for (int c = 0; c < 32; ++c) {
      a1[c] = *(const h2*)&sFB[(2 * t) * 72 + 2 * c];
      a2[c] = *(const h2*)&sFB[(2 * t + 1) * 72 + 2 * c];
    }
    #pragma unroll
    for (int c = 0; c < 32; ++c) {
      aa1 = __builtin_amdgcn_fdot2(a1[c], a1[c], aa1, false);
      aa2 = __builtin_amdgcn_fdot2(a2[c], a2[c], aa2, false);
    }
    aa1 *= 0.5f; aa2 *= 0.5f;
  }
  __syncthreads();
  stage(Bp);
  __syncthreads();
  {
    #pragma unroll
    for (int rr = 0; rr < 2; ++rr) {
      int r = 2 * t + rr;
      float s = 0.f;
      #pragma unroll
      for (int c = 0; c < 32; ++c) {
        h2 bv = *(const h2*)&sFB[r * 72 + 2 * c];
        s = __builtin_amdgcn_fdot2(bv, bv, s, false);
      }
      sbb[r] = 0.5f * s;
    }
    vbuf[0][t] = BIGV; vbuf[1][t] = BIGV; vbuf[2][t] = BIGV;
  }
  __syncthreads();
  float vL1 = BIGV, vL2 = BIGV;
  int cur = 2, p1 = 1, p2 = 0;
  for (int s = 1; s <= TT + 127; ++s) {
    const int j = s - t;
    float up1, dg1;
    if (t == 0) { up1 = BIGV; dg1 = (s == 1) ? 0.0f : BIGV; }
    else { up1 = vbuf[p1][t - 1]; dg1 = vbuf[p2][t - 1]; }
    float wv = BIGV;
    if (j >= 1 && j <= TT) {
      float d1 = 0.f, d2 = 0.f;
      #pragma unroll
      for (int c = 0; c < 32; ++c) {
        h2 bv = *(const h2*)&sFB[(j - 1) * 72 + 2 * c];
        d1 = __builtin_amdgcn_fdot2(a1[c], bv, d1, false);
        d2 = __builtin_amdgcn_fdot2(a2[c], bv, d2, false);
      }
      float bbj = sbb[j - 1];
      float c1 = aa1 + bbj - d1;
      float c2 = aa2 + bbj - d2;
      float l1 = (j == 1) ? BIGV : vL1;
      float v1 = c1 + softmin3(l1, dg1, up1);
      float dg2 = l1;
      float l2 = (j == 1) ? BIGV : vL2;
      float v2 = c2 + softmin3(l2, dg2, v1);
      vL1 = v1; vL2 = v2; wv = v2;
    }
    vbuf[cur][t] = wv;
    int tmp = p2; p2 = p1; p1 = cur; cur = tmp;
    __syncthreads();
  }
  if (t == 127) atomicAdd(out, w * vL2);
}

extern "C" void kernel_launch(void* const* d_in, const int* in_sizes, int n_in,
                              void* d_out, int out_size, void* d_ws, size_t ws_size,
                              hipStream_t stream) {
  const float* X = (const float*)d_in[0];
  const float* Y = (const float*)d_in[1];
  float* out = (float*)d_out;
  hipMemsetAsync(out, 0, sizeof(float) * out_size, stream);

  size_t chunk = ws_size / SLAB;
  if (chunk >= 1) {
    if (chunk > NPROB) chunk = NPROB;
    unsigned char* ws = (unsigned char*)d_ws;
    for (int q0 = 0; q0 < NPROB; q0 += (int)chunk) {
      int n = (NPROB - q0 < (int)chunk) ? NPROB - q0 : (int)chunk;
      cost_kernel<<<n, 256, 0, stream>>>(X, Y, ws, q0);
      dp_kernel<<<n, 64, 0, stream>>>(ws, out, q0);
    }
  } else {
    dim3 grid(512, 3);
    sdtw_fused<<<grid, 128, 0, stream>>>(X, Y, out);
  }
}

// Round 5
// 144.591 us; speedup vs baseline: 5.9318x; 1.2645x over previous
//
#include <hip/hip_runtime.h>

typedef _Float16 h2 __attribute__((ext_vector_type(2)));
typedef _Float16 h8 __attribute__((ext_vector_type(8)));
typedef float f4 __attribute__((ext_vector_type(4)));

#define TT 256
#define KK 64
#define BIGV 1e10f
#define LOG2E 1.44269504f
#define LN2 0.69314718f
#define RL 32      // ring lines (diagonals); live window <= 19
#define RSTR 65    // ring line stride in u32 (padded: banks (s1+t)%32 -> conflict-free reads)

// softmin in log2-scaled domain (values pre-scaled by log2e): exact correspondence.
__device__ __forceinline__ float softmin3b(float a, float b, float c) {
  float m, d, M;
  asm("v_min3_f32 %0, %1, %2, %3" : "=v"(m) : "v"(a), "v"(b), "v"(c));
  asm("v_max3_f32 %0, %1, %2, %3" : "=v"(M) : "v"(a), "v"(b), "v"(c));
  asm("v_med3_f32 %0, %1, %2, %3" : "=v"(d) : "v"(a), "v"(b), "v"(c));
  float s = 1.0f + __builtin_amdgcn_exp2f(m - d) + __builtin_amdgcn_exp2f(m - M);
  return m - __log2f(s);
}

// One wave per problem: MFMA cost tiles in anti-diagonal key order feed a 32-line
// LDS ring; wave-synchronous DP (4 rows/lane) consumes 4 steps per key. No barriers,
// no global intermediate.
__global__ __launch_bounds__(64, 2)
void sdtw_fused1(const float* __restrict__ X, const float* __restrict__ Y,
                 float* __restrict__ out) {
  const int p = blockIdx.x;
  const int type = p >> 9;            // 0: xy, 1: xx, 2: yy
  const int b = p & 511;
  const float* Ap = (type == 2 ? Y : X) + (size_t)b * TT * KK;
  const float* Bp = (type == 1 ? X : Y) + (size_t)b * TT * KK;
  const float wgt = (type == 0) ? (LN2 / 512.0f) : (-LN2 / 1024.0f);  // back to e-domain

  __shared__ unsigned int ring0[RL * RSTR];   // f16x2: rows 4t+1,4t+2
  __shared__ unsigned int ring1[RL * RSTR];   // f16x2: rows 4t+3,4t+4
  __shared__ float saa[TT];                   // 0.5*log2e*||A_r||^2
  __shared__ float sbb[TT];                   // 0.5*log2e*||B_r||^2

  const int t = threadIdx.x;
  const int hk = t >> 4, lr = t & 15;

  // ---- zero-init ring (invalid slots must read as cost 0 >= 0) ----
  #pragma unroll
  for (int i = 0; i < 33; ++i) {
    int idx = i * 64 + t;
    if (idx < RL * RSTR) { ring0[idx] = 0u; ring1[idx] = 0u; }
  }

  // ---- A fragments -> registers (f16) + row norms via in-register reduce ----
  h8 af[16][2];
  #pragma unroll
  for (int Rt = 0; Rt < 16; ++Rt) {
    float s = 0.f;
    #pragma unroll
    for (int kk = 0; kk < 2; ++kk) {
      const float4* src = (const float4*)(Ap + (Rt * 16 + lr) * KK + kk * 32 + hk * 8);
      float4 x = src[0], y = src[1];
      af[Rt][kk] = (h8){(_Float16)x.x, (_Float16)x.y, (_Float16)x.z, (_Float16)x.w,
                        (_Float16)y.x, (_Float16)y.y, (_Float16)y.z, (_Float16)y.w};
      s += x.x * x.x + x.y * x.y + x.z * x.z + x.w * x.w
         + y.x * y.x + y.y * y.y + y.z * y.z + y.w * y.w;
    }
    s += __shfl_xor(s, 16);
    s += __shfl_xor(s, 32);
    if (hk == (Rt & 3)) saa[Rt * 16 + lr] = 0.5f * LOG2E * s;
  }

  h8 bwin[4][2];                      // sliding B-fragment window, slot = Ct & 3
  float vL1 = BIGV, vL2 = BIGV, vL3 = BIGV, vL4 = BIGV;
  float dg = (t == 0) ? 0.0f : BIGV;  // V[i1-1][j-1]; at s=1 lane0: V[0][0]=0

  #pragma unroll 1
  for (int kbo = 0; kbo < 5; ++kbo) {
    #pragma unroll
    for (int q = 0; q < 4; ++q) {
      const int KB = kbo * 4 + q;     // KB = k>>2, 0..18 (KB=19 skipped)
      // ---- load B-fragment Ct=KB into slot q (= KB&3), norms just-in-time ----
      if (KB <= 15) {
        float s2 = 0.f;
        #pragma unroll
        for (int kk = 0; kk < 2; ++kk) {
          const float4* src = (const float4*)(Bp + (KB * 16 + lr) * KK + kk * 32 + hk * 8);
          float4 x = src[0], y = src[1];
          bwin[q][kk] = (h8){(_Float16)x.x, (_Float16)x.y, (_Float16)x.z, (_Float16)x.w,
                             (_Float16)y.x, (_Float16)y.y, (_Float16)y.z, (_Float16)y.w};
          s2 += x.x * x.x + x.y * x.y + x.z * x.z + x.w * x.w
              + y.x * y.x + y.y * y.y + y.z * y.z + y.w * y.w;
        }
        s2 += __shfl_xor(s2, 16);
        s2 += __shfl_xor(s2, 32);
        if (hk == 0) sbb[KB * 16 + lr] = 0.5f * LOG2E * s2;
      }
      if (KB <= 18) {
        #pragma unroll
        for (int r = 0; r < 4; ++r) {
          const int k = KB * 4 + r;   // tile key 4*Ct+Rt, 0..75
          // ---- produce tiles of key k: (Rt = r+4d, Ct = KB-d) ----
          #pragma unroll
          for (int dlt = 0; dlt < 4; ++dlt) {
            if (dlt <= KB && dlt >= KB - 15) {
              const int Rt = r + 4 * dlt;          // compile-time
              const int Ct = KB - dlt;
              const int slot = (q - dlt) & 3;      // compile-time
              f4 acc = {0.f, 0.f, 0.f, 0.f};
              acc = __builtin_amdgcn_mfma_f32_16x16x32_f16(af[Rt][0], bwin[slot][0], acc, 0, 0, 0);
              acc = __builtin_amdgcn_mfma_f32_16x16x32_f16(af[Rt][1], bwin[slot][1], acc, 0, 0, 0);
              const int r0 = Rt * 16 + hk * 4;
              f4 aav = *(const f4*)&saa[r0];
              float bbv = sbb[Ct * 16 + lr];
              float c0 = fmaf(-LOG2E, acc.x, aav.x + bbv);
              float c1 = fmaf(-LOG2E, acc.y, aav.y + bbv);
              float c2 = fmaf(-LOG2E, acc.z, aav.z + bbv);
              float c3 = fmaf(-LOG2E, acc.w, aav.w + bbv);
              const int t_row = 4 * Rt + hk;
              const int s1 = Ct * 16 + lr + t_row; // diagonal line index
              const int widx = (s1 & 31) * RSTR + t_row;
              ring0[widx] = __builtin_bit_cast(unsigned int, __builtin_amdgcn_cvt_pkrtz(c0, c1));
              ring1[widx] = __builtin_bit_cast(unsigned int, __builtin_amdgcn_cvt_pkrtz(c2, c3));
            }
          }
          // ---- 4 DP steps: s = 4k+1 .. 4k+4 (lines 4k..4k+3 complete) ----
          unsigned int w0[4], w1[4];
          #pragma unroll
          for (int u = 0; u < 4; ++u) {
            const int s1 = 4 * k + u;
            const int ridx = (s1 & 31) * RSTR + t;
            w0[u] = ring0[ridx];
            w1[u] = ring1[ridx];
          }
          #pragma unroll
          for (int u = 0; u < 4; ++u) {
            float up1 = __shfl_up(vL4, 1);
            if (t == 0) up1 = BIGV;
            h2 cA = __builtin_bit_cast(h2, w0[u]);
            h2 cB = __builtin_bit_cast(h2, w1[u]);
            float v1 = (float)cA[0] + softmin3b(vL1, dg, up1);
            float v2 = (float)cA[1] + softmin3b(vL2, vL1, v1);
            float v3 = (float)cB[0] + softmin3b(vL3, vL2, v2);
            float v4 = (float)cB[1] + softmin3b(vL4, vL3, v3);
            vL1 = v1; vL2 = v2; vL3 = v3; vL4 = v4; dg = up1;
          }
        }
      }
    }
  }

  // ---- tail: s = 305..319 (all lines complete after key 75) ----
  #pragma unroll
  for (int u = 0; u < 15; ++u) {
    const int s1 = 304 + u;
    const int ridx = (s1 & 31) * RSTR + t;
    unsigned int a0 = ring0[ridx];
    unsigned int a1 = ring1[ridx];
    float up1 = __shfl_up(vL4, 1);
    if (t == 0) up1 = BIGV;
    h2 cA = __builtin_bit_cast(h2, a0);
    h2 cB = __builtin_bit_cast(h2, a1);
    float v1 = (float)cA[0] + softmin3b(vL1, dg, up1);
    float v2 = (float)cA[1] + softmin3b(vL2, vL1, v1);
    float v3 = (float)cB[0] + softmin3b(vL3, vL2, v2);
    float v4 = (float)cB[1] + softmin3b(vL4, vL3, v3);
    vL1 = v1; vL2 = v2; vL3 = v3; vL4 = v4; dg = up1;
  }

  // lane 63 holds V[256][256] (log2 domain)
  if (t == 63) atomicAdd(out, wgt * vL4);
}

extern "C" void kernel_launch(void* const* d_in, const int* in_sizes, int n_in,
                              void* d_out, int out_size, void* d_ws, size_t ws_size,
                              hipStream_t stream) {
  const float* X = (const float*)d_in[0];
  const float* Y = (const float*)d_in[1];
  float* out = (float*)d_out;
  hipMemsetAsync(out, 0, sizeof(float) * out_size, stream);
  sdtw_fused1<<<1536, 64, 0, stream>>>(X, Y, out);
}